// Round 7
// baseline (678.219 us; speedup 1.0000x reference)
//
#include <hip/hip_runtime.h>
#include <math.h>

#define HD 1024
#define S1 150
#define BATCH 128
#define MTOK (S1 * BATCH) /* 19200 */
#define WIN 20
#define QKVLD (3 * HD) /* 3072 */

typedef unsigned short bf16_t;
typedef short s16x8 __attribute__((ext_vector_type(8)));
typedef float f32x4 __attribute__((ext_vector_type(4)));
typedef float f32x16 __attribute__((ext_vector_type(16)));

__device__ __forceinline__ float bf2f(unsigned int u16) {
  return __uint_as_float(u16 << 16);
}
__device__ __forceinline__ unsigned short f2bf(float f) {
  unsigned int u = __float_as_uint(f);
  u += 0x7fff + ((u >> 16) & 1);  // RNE
  return (unsigned short)(u >> 16);
}

__device__ __forceinline__ float wave_sum(float v) {
#pragma unroll
  for (int o = 32; o; o >>= 1) v += __shfl_down(v, o, 64);
  return v;
}

// async 16B/lane global->LDS. LDS dest = wave-uniform base + lane*16.
__device__ __forceinline__ void gload_lds16(const bf16_t* g, bf16_t* l) {
  __builtin_amdgcn_global_load_lds(
      (const __attribute__((address_space(1))) unsigned int*)(unsigned long long)(const void*)g,
      (__attribute__((address_space(3))) unsigned int*)(unsigned int)(unsigned long long)(void*)l,
      16, 0, 0);
}

// ---------------- merged weight transpose: WT[n][k] = bf16(W[k][n]) -------
__global__ __launch_bounds__(256) void transpose_all_kernel(
    const float* __restrict__ w_qkv, bf16_t* __restrict__ wt_qkv,
    const float* __restrict__ w_o, bf16_t* __restrict__ wt_o,
    const float* __restrict__ w_m1, bf16_t* __restrict__ wt_m1,
    const float* __restrict__ w_m2, bf16_t* __restrict__ wt_m2) {
  int g = blockIdx.x;
  const float* W;
  bf16_t* WT;
  int N, bx, by;
  if (g < 3072) {
    W = w_qkv; WT = wt_qkv; N = 3072;
    bx = g % 96; by = g / 96;
  } else {
    int r = g - 3072;
    int which = r >> 10, l = r & 1023;
    bx = l & 31; by = l >> 5; N = 1024;
    W = (which == 0) ? w_o : (which == 1) ? w_m1 : w_m2;
    WT = (which == 0) ? wt_o : (which == 1) ? wt_m1 : wt_m2;
  }
  __shared__ float t[32][33];
  int n0 = bx * 32, k0 = by * 32;
  int tx = threadIdx.x, ty = threadIdx.y;
#pragma unroll
  for (int i = 0; i < 4; i++)
    t[ty + i * 8][tx] = W[(size_t)(k0 + ty + i * 8) * N + n0 + tx];
  __syncthreads();
#pragma unroll
  for (int i = 0; i < 4; i++)
    WT[(size_t)(n0 + ty + i * 8) * 1024 + k0 + tx] = f2bf(t[tx][ty + i * 8]);
}

// ---------------- PE table ------------------------------------------------
__global__ void pe_kernel(float* __restrict__ pe) {
  int s = blockIdx.x;
  double pos = 6.283185307179586476925286766559 * (double)s;
  for (int p = threadIdx.x; p < HD / 2; p += blockDim.x) {
    double dv = exp((double)(2 * p) * (-9.210340371976184 / (double)HD));
    double a = pos * dv;
    pe[s * HD + 2 * p] = (float)sin(a);
    pe[s * HD + 2 * p + 1] = (float)cos(a);
  }
}

// ---------------- x = bf16(LN(concat(cls, z^T) + pe)) ---------------------
__global__ __launch_bounds__(256) void build_x_kernel(
    const float* __restrict__ z, const float* __restrict__ cls,
    const float* __restrict__ pe, const float* __restrict__ g,
    const float* __restrict__ be, bf16_t* __restrict__ x) {
  int t = blockIdx.x;
  int b = t / S1, s = t % S1;
  const float* src = (s == 0) ? cls : (z + ((size_t)(s - 1) * BATCH + b) * HD);
  const float* pr = pe + (size_t)s * HD;
  int tid = threadIdx.x;
  float vals[4];
  float sum = 0.f, sq = 0.f;
#pragma unroll
  for (int i = 0; i < 4; i++) {
    int h = tid + i * 256;
    float v = src[h] + pr[h];
    vals[i] = v;
    sum += v;
    sq += v * v;
  }
  __shared__ float shs[4], shq[4];
  __shared__ float sm, sr;
  sum = wave_sum(sum);
  sq = wave_sum(sq);
  int wave = tid >> 6, lane = tid & 63;
  if (!lane) { shs[wave] = sum; shq[wave] = sq; }
  __syncthreads();
  if (!tid) {
    float S = shs[0] + shs[1] + shs[2] + shs[3];
    float Q = shq[0] + shq[1] + shq[2] + shq[3];
    float mean = S * (1.f / HD);
    float var = Q * (1.f / HD) - mean * mean;
    sm = mean;
    sr = rsqrtf(var + 1e-5f);
  }
  __syncthreads();
  float mean = sm, rstd = sr;
  bf16_t* xr = x + (size_t)t * HD;
#pragma unroll
  for (int i = 0; i < 4; i++) {
    int h = tid + i * 256;
    xr[h] = f2bf((vals[i] - mean) * rstd * g[h] + be[h]);
  }
}

// ---------------- zsa = bf16(LN(sa + x)) ----------------------------------
__global__ __launch_bounds__(256) void ln_residual_kernel(
    const bf16_t* __restrict__ a, const bf16_t* __restrict__ r,
    const float* __restrict__ g, const float* __restrict__ be,
    bf16_t* __restrict__ out) {
  int t = blockIdx.x;
  int tid = threadIdx.x;
  const bf16_t* ar = a + (size_t)t * QKVLD;
  const bf16_t* rr = r + (size_t)t * HD;
  float vals[4];
  float sum = 0.f, sq = 0.f;
#pragma unroll
  for (int i = 0; i < 4; i++) {
    int h = tid + i * 256;
    float v = bf2f(ar[h]) + bf2f(rr[h]);
    vals[i] = v;
    sum += v;
    sq += v * v;
  }
  __shared__ float shs[4], shq[4];
  __shared__ float sm, sr;
  sum = wave_sum(sum);
  sq = wave_sum(sq);
  int wave = tid >> 6, lane = tid & 63;
  if (!lane) { shs[wave] = sum; shq[wave] = sq; }
  __syncthreads();
  if (!tid) {
    float S = shs[0] + shs[1] + shs[2] + shs[3];
    float Q = shq[0] + shq[1] + shq[2] + shq[3];
    float mean = S * (1.f / HD);
    float var = Q * (1.f / HD) - mean * mean;
    sm = mean;
    sr = rsqrtf(var + 1e-5f);
  }
  __syncthreads();
  float mean = sm, rstd = sr;
  bf16_t* outp = out + (size_t)t * QKVLD;
#pragma unroll
  for (int i = 0; i < 4; i++) {
    int h = tid + i * 256;
    outp[h] = f2bf((vals[i] - mean) * rstd * g[h] + be[h]);
  }
}

// ---------------- 128x128 MFMA GEMM, BK=64, 32x32x16 MFMA -----------------
// Staging + LDS layout byte-identical to the harness-proven kernel
// (16-row x 32-col units, granule swizzle LDS[r][q] = glob[r][q^((r>>1)&3)]).
// New: v_mfma_f32_32x32x16_bf16 (2382 TF ubench vs 2075 for 16x16; half the
// issue slots). Per wave: 2x2 tiles of 32x32. A-frag: row=lane&31,
// k-granule=2h+(lane>>5); C/D (m101): col=lane&31,
// row=(reg&3)+8*(reg>>2)+4*(lane>>5).
// EPI: 0 = bias, 1 = bias+GELU (LDS-staged coalesced store),
//      2 = bias+residual -> f32 out (s,b swizzle)
template <int EPI>
__global__ __launch_bounds__(256) void mfma_gemm_kernel(
    const bf16_t* __restrict__ A, int lda, const bf16_t* __restrict__ WT,
    const float* __restrict__ bias, bf16_t* __restrict__ C, int ldc,
    const bf16_t* __restrict__ res, float* __restrict__ outf) {
  constexpr int K = 1024;
  __shared__ bf16_t SMEM[16384];  // K-loop: A [0,8192) B [8192,16384); epi: C tile
  bf16_t* As = SMEM;
  bf16_t* Bs = SMEM + 8192;
  int tid = threadIdx.x;
  int w = tid >> 6, lane = tid & 63;
  int wm = w >> 1, wn = w & 1;
  int m0 = blockIdx.y * 128, n0 = blockIdx.x * 128;

  int srow = lane >> 2;
  int scol = ((lane & 3) ^ ((lane >> 3) & 3)) * 8;
  const bf16_t* gA0 = A + (size_t)(m0 + w * 32 + srow) * lda + scol;
  const bf16_t* gA1 = gA0 + (size_t)16 * lda;
  const bf16_t* gB0 = WT + (size_t)(n0 + w * 32 + srow) * K + scol;
  const bf16_t* gB1 = gB0 + (size_t)16 * K;
  bf16_t* lA0 = As + (w * 32) * 32;
  bf16_t* lA1 = As + (w * 32 + 16) * 32;
  bf16_t* lB0 = Bs + (w * 32) * 32;
  bf16_t* lB1 = Bs + (w * 32 + 16) * 32;

  // 32x32x16 fragment read offsets: row = lane&31 within each 32-row tile,
  // global k-granule (within 32-col plane) = 2h + (lane>>5), de-swizzled.
  int r32 = lane & 31, g5 = lane >> 5;
  int aoff[2][2], boff[2][2];  // [tile][h]
#pragma unroll
  for (int mi = 0; mi < 2; mi++) {
    int arow = wm * 64 + mi * 32 + r32;
    int brow = wn * 64 + mi * 32 + r32;
#pragma unroll
    for (int h = 0; h < 2; h++) {
      aoff[mi][h] = arow * 32 + (((2 * h + g5) ^ ((arow >> 1) & 3))) * 8;
      boff[mi][h] = brow * 32 + (((2 * h + g5) ^ ((brow >> 1) & 3))) * 8;
    }
  }

  f32x16 acc[2][2] = {};

  for (int k0 = 0; k0 < K; k0 += 64) {
    // plane 0: cols [k0, k0+32), plane 1: cols [k0+32, k0+64)
    gload_lds16(gA0, lA0);
    gload_lds16(gA1, lA1);
    gload_lds16(gB0, lB0);
    gload_lds16(gB1, lB1);
    gload_lds16(gA0 + 32, lA0 + 4096);
    gload_lds16(gA1 + 32, lA1 + 4096);
    gload_lds16(gB0 + 32, lB0 + 4096);
    gload_lds16(gB1 + 32, lB1 + 4096);
    gA0 += 64; gA1 += 64; gB0 += 64; gB1 += 64;
    __syncthreads();
#pragma unroll
    for (int p = 0; p < 2; p++) {
      s16x8 af[2][2], bf[2][2];
#pragma unroll
      for (int t = 0; t < 2; t++)
#pragma unroll
        for (int h = 0; h < 2; h++) {
          af[t][h] = *(const s16x8*)(As + p * 4096 + aoff[t][h]);
          bf[t][h] = *(const s16x8*)(Bs + p * 4096 + boff[t][h]);
        }
#pragma unroll
      for (int mi = 0; mi < 2; mi++)
#pragma unroll
        for (int nj = 0; nj < 2; nj++)
#pragma unroll
          for (int h = 0; h < 2; h++)
            acc[mi][nj] = __builtin_amdgcn_mfma_f32_32x32x16_bf16(
                af[mi][h], bf[nj][h], acc[mi][nj], 0, 0, 0);
    }
    __syncthreads();
  }

  if (EPI == 2) {
    // residual + f32 out in (s,b)-swizzled layout
#pragma unroll
    for (int nj = 0; nj < 2; nj++) {
#pragma unroll
      for (int mi = 0; mi < 2; mi++) {
        int n = n0 + wn * 64 + nj * 32 + r32;
        float bb = bias[n];
#pragma unroll
        for (int r = 0; r < 16; r++) {
          int rrow = (r & 3) + 8 * (r >> 2) + 4 * g5;
          int m = m0 + wm * 64 + mi * 32 + rrow;
          int b = m / S1, s = m % S1;
          float v = acc[mi][nj][r] + bb + bf2f(res[(size_t)m * QKVLD + n]);
          outf[((size_t)s * BATCH + b) * HD + n] = v;
        }
      }
    }
  } else {
    // stage C tile (bf16) in SMEM, then full-line coalesced uint4 stores
#pragma unroll
    for (int nj = 0; nj < 2; nj++) {
      int cn = wn * 64 + nj * 32 + r32;
      float bb = bias[n0 + cn];
#pragma unroll
      for (int mi = 0; mi < 2; mi++) {
#pragma unroll
        for (int r = 0; r < 16; r++) {
          int rrow = (r & 3) + 8 * (r >> 2) + 4 * g5;
          int cm = wm * 64 + mi * 32 + rrow;
          float v = acc[mi][nj][r] + bb;
          if (EPI == 1) v = 0.5f * v * (1.f + erff(v * 0.7071067811865476f));
          SMEM[cm * 128 + cn] = f2bf(v);
        }
      }
    }
    __syncthreads();
    int rr = tid >> 4, cb = (tid & 15) * 8;
#pragma unroll
    for (int p = 0; p < 8; p++) {
      int row = p * 16 + rr;
      *(uint4*)(C + (size_t)(m0 + row) * ldc + n0 + cb) =
          *(const uint4*)(SMEM + row * 128 + cb);
    }
  }
}

// ---------------- tiled band attention: MFMA QK^T + LDS softmax + VALU PV -
__global__ __launch_bounds__(256) void attn_tile_kernel(bf16_t* __restrict__ qkv) {
  int g = blockIdx.x;
  int xcd = g & 7, tt0 = g >> 3;
  int qt = tt0 % 5, b = xcd + 8 * (tt0 / 5);
  int q0 = qt * 32;

  int lo_col = (qt == 0) ? 0 : (q0 - 20);
  int hi_col = (qt == 0) ? 150 : ((q0 + 51 < 150) ? q0 + 51 : 150);
  int ct0 = lo_col >> 5;
  int cth = (hi_col + 31) >> 5;
  int NCT = cth - ct0;       // 5,3,3,3,2
  int W = NCT * 32;          // score width
  int NSUB = NCT * 2;        // 16-wide column subtiles
  int NT = 2 * NSUB;         // total 16x16 tiles (20,12,12,12,8)
  int T = NT >> 2;           // tiles per wave (5,3,3,3,2)

  __shared__ bf16_t Qs[2 * 32 * 32];    // 2 k-planes of Q tile
  __shared__ bf16_t Ks[2 * 160 * 32];   // 2 k-planes of K band
  __shared__ float S[32][164];          // scores -> probs (f32)

  int tid = threadIdx.x;
  int w = tid >> 6, lane = tid & 63;

  const bf16_t* kvbase = qkv + (size_t)b * S1 * QKVLD;

  int sr = lane >> 2;                                 // row within 16-row unit
  int scol = ((lane & 3) ^ ((lane >> 3) & 3)) * 8;    // swizzled 8-elem slot
  int frow = lane & 15;
  int fslot = (((lane >> 4) ^ ((frow >> 1) & 3))) * 8;

  f32x4 acc[5] = {};

  int U1 = 2 + NSUB;  // 16-row staging units per k-plane (Q:2, K:NSUB)

  for (int k0 = 0; k0 < 1024; k0 += 64) {
    for (int uu = w; uu < 2 * U1; uu += 4) {
      int p = (uu >= U1) ? 1 : 0;
      int ur = uu - p * U1;
      int col = k0 + p * 32 + scol;
      if (ur < 2) {
        int qrow = q0 + ur * 16 + sr;
        if (qrow > 149) qrow = 149;
        gload_lds16(kvbase + (size_t)qrow * QKVLD + col,
                    Qs + p * 1024 + (ur * 16) * 32);
      } else {
        int cr0 = (ur - 2) * 16;             // c_rel row base of unit
        int cg = ct0 * 32 + cr0 + sr;
        if (cg > 149) cg = 149;
        gload_lds16(kvbase + (size_t)cg * QKVLD + HD + col,
                    Ks + p * 5120 + cr0 * 32);
      }
    }
    __syncthreads();
    s16x8 af0[2], af1[2];
#pragma unroll
    for (int p = 0; p < 2; p++) {
      af0[p] = *(const s16x8*)(Qs + p * 1024 + (0 * 16 + frow) * 32 + fslot);
      af1[p] = *(const s16x8*)(Qs + p * 1024 + (1 * 16 + frow) * 32 + fslot);
    }
#pragma unroll
    for (int t = 0; t < 5; t++) {
      if (t < T) {
        int tidt = w + t * 4;
        int qs = (tidt >= NSUB) ? 1 : 0;
        int cs = tidt - qs * NSUB;
#pragma unroll
        for (int p = 0; p < 2; p++) {
          s16x8 bf = *(const s16x8*)(Ks + p * 5120 + (cs * 16 + frow) * 32 + fslot);
          s16x8 a = qs ? af1[p] : af0[p];
          acc[t] = __builtin_amdgcn_mfma_f32_16x16x32_bf16(a, bf, acc[t], 0, 0, 0);
        }
      }
    }
    __syncthreads();
  }

  // write scores to LDS with mask+scale fused (C/D: col=lane&15, row=(lane>>4)*4+r)
  int erow = (lane >> 4) * 4, ecol = lane & 15;
#pragma unroll
  for (int t = 0; t < 5; t++) {
    if (t < T) {
      int tidt = w + t * 4;
      int qs = (tidt >= NSUB) ? 1 : 0;
      int cs = tidt - qs * NSUB;
#pragma unroll
      for (int r = 0; r < 4; r++) {
        int qrel = qs * 16 + erow + r;
        int crel = cs * 16 + ecol;
        int qg = q0 + qrel, cg = ct0 * 32 + crel;
        bool ok = (qg < 150) && (cg < 150) &&
                  ((qg == 0) || (cg >= qg - WIN && cg < qg + WIN));
        S[qrel][crel] = ok ? acc[t][r] * 0.03125f : -1e30f;
      }
    }
  }
  __syncthreads();

  // softmax: 8 threads per query row, shfl_xor reduce over 8 lanes
  {
    int q = tid >> 3, j = tid & 7;
    float m = -1e30f;
    for (int c = j; c < W; c += 8) m = fmaxf(m, S[q][c]);
#pragma unroll
    for (int o = 1; o < 8; o <<= 1) m = fmaxf(m, __shfl_xor(m, o, 64));
    float s = 0.f;
    for (int c = j; c < W; c += 8) {
      float e = __expf(S[q][c] - m);
      S[q][c] = e;
      s += e;
    }
#pragma unroll
    for (int o = 1; o < 8; o <<= 1) s += __shfl_xor(s, o, 64);
    float inv = 1.f / s;
    for (int c = j; c < W; c += 8) S[q][c] *= inv;
  }
  __syncthreads();

  // PV: wave owns an 8-query octet; P broadcast from LDS, V coalesced from L2.
  // cls octet (qt==0, w==0): row 0 attends to ALL columns -> full range;
  // rows 1..7 of that octet are safe since their masked probs are exactly 0.
  int qg0 = q0 + 8 * w;
  if (qg0 < 150) {
    int lo = (qt == 0 && w == 0) ? 0 : ((qg0 - WIN > 0) ? qg0 - WIN : 0);
    int hi = (qt == 0 && w == 0) ? 150 : ((qg0 + 27 < 150) ? qg0 + 27 : 150);
    int c0base = ct0 * 32;
#pragma unroll
    for (int hp = 0; hp < 2; hp++) {
      int hb = hp * 512 + lane * 8;
      float a[8][8];
#pragma unroll
      for (int qi = 0; qi < 8; qi++)
#pragma unroll
        for (int e = 0; e < 8; e++) a[qi][e] = 0.f;
      const bf16_t* vb = kvbase + 2 * HD + hb;
      for (int c = lo; c < hi; ++c) {
        uint4 vv = *(const uint4*)(vb + (size_t)c * QKVLD);
        float vf[8];
        vf[0] = __uint_as_float(vv.x << 16);
        vf[1] = __uint_as_float(vv.x & 0xffff0000u);
        vf[2] = __uint_as_float(vv.y << 16);
        vf[3] = __uint_as_float(vv.y & 0xffff0000u);
        vf[4] = __uint_as_float(vv.z << 16);
        vf[5] = __uint_as_float(vv.z & 0xffff0000u);
        vf[6] = __uint_as_float(vv.w << 16);
        vf[7] = __uint_as_float(vv.w & 0xffff0000u);
        int crel = c - c0base;
#pragma unroll
        for (int qi = 0; qi < 8; qi++) {
          float p = S[8 * w + qi][crel];
#pragma unroll
          for (int e = 0; e < 8; e++) a[qi][e] += p * vf[e];
        }
      }
#pragma unroll
      for (int qi = 0; qi < 8; qi++) {
        int qg = qg0 + qi;
        if (qg < 150) {
          uint4 pk;
          pk.x = (unsigned int)f2bf(a[qi][0]) | ((unsigned int)f2bf(a[qi][1]) << 16);
          pk.y = (unsigned int)f2bf(a[qi][2]) | ((unsigned int)f2bf(a[qi][3]) << 16);
          pk.z = (unsigned int)f2bf(a[qi][4]) | ((unsigned int)f2bf(a[qi][5]) << 16);
          pk.w = (unsigned int)f2bf(a[qi][6]) | ((unsigned int)f2bf(a[qi][7]) << 16);
          *(uint4*)(qkv + ((size_t)b * S1 + qg) * QKVLD + hb) = pk;
        }
      }
    }
  }
}

extern "C" void kernel_launch(void* const* d_in, const int* in_sizes, int n_in,
                              void* d_out, int out_size, void* d_ws, size_t ws_size,
                              hipStream_t stream) {
  (void)in_sizes; (void)n_in; (void)out_size; (void)ws_size;
  const float* z = (const float*)d_in[0];
  const float* cls = (const float*)d_in[1];
  const float* ln_g = (const float*)d_in[2];
  const float* ln_b = (const float*)d_in[3];
  const float* w_qkv = (const float*)d_in[4];
  const float* b_qkv = (const float*)d_in[5];
  const float* w_o = (const float*)d_in[6];
  const float* b_o = (const float*)d_in[7];
  const float* w_m1 = (const float*)d_in[8];
  const float* b_m1 = (const float*)d_in[9];
  const float* w_m2 = (const float*)d_in[10];
  const float* b_m2 = (const float*)d_in[11];

  // ws: [wt_m2 2MB][pe 0.6MB][qkv 118MB] = ~120.7 MB
  char* wsb = (char*)d_ws;
  bf16_t* wt_m2 = (bf16_t*)wsb;
  float* pe = (float*)(wsb + 2097152);
  bf16_t* qkv = (bf16_t*)(wsb + 2097152 + 614400);

  // d_out scratch: [x bf16 39.3MB][wt_qkv 6.3MB][wt_o 2MB][wt_m1 2MB]
  char* outb = (char*)d_out;
  bf16_t* x = (bf16_t*)outb;
  bf16_t* wt_qkv = (bf16_t*)(outb + 39321600);
  bf16_t* wt_o = (bf16_t*)(outb + 45613056);
  bf16_t* wt_m1 = (bf16_t*)(outb + 47710208);

  bf16_t* av = qkv;            // attention writes over Q slice
  bf16_t* sa = qkv + HD;       // over K slice
  bf16_t* zsa = qkv + 2 * HD;  // over V slice
  bf16_t* h1 = qkv;            // over Q slice (av dead)
  float* out = (float*)d_out;

  transpose_all_kernel<<<6144, dim3(32, 8), 0, stream>>>(
      w_qkv, wt_qkv, w_o, wt_o, w_m1, wt_m1, w_m2, wt_m2);
  pe_kernel<<<S1, 256, 0, stream>>>(pe);
  build_x_kernel<<<MTOK, 256, 0, stream>>>(z, cls, pe, ln_g, ln_b, x);
  mfma_gemm_kernel<0><<<dim3(24, 150), 256, 0, stream>>>(
      x, HD, wt_qkv, b_qkv, qkv, QKVLD, nullptr, nullptr);
  attn_tile_kernel<<<640, 256, 0, stream>>>(qkv);
  mfma_gemm_kernel<0><<<dim3(8, 150), 256, 0, stream>>>(
      av, QKVLD, wt_o, b_o, sa, QKVLD, nullptr, nullptr);
  ln_residual_kernel<<<MTOK, 256, 0, stream>>>(sa, x, ln_g, ln_b, zsa);
  mfma_gemm_kernel<1><<<dim3(8, 150), 256, 0, stream>>>(
      zsa, QKVLD, wt_m1, b_m1, h1, QKVLD, nullptr, nullptr);
  mfma_gemm_kernel<2><<<dim3(8, 150), 256, 0, stream>>>(
      h1, QKVLD, wt_m2, b_m2, nullptr, 0, zsa, out);
}

// Round 8
// 662.708 us; speedup vs baseline: 1.0234x; 1.0234x over previous
//
#include <hip/hip_runtime.h>
#include <math.h>

#define HD 1024
#define S1 150
#define BATCH 128
#define MTOK (S1 * BATCH) /* 19200 */
#define WIN 20
#define QKVLD (3 * HD) /* 3072 */

typedef unsigned short bf16_t;
typedef short s16x8 __attribute__((ext_vector_type(8)));
typedef float f32x4 __attribute__((ext_vector_type(4)));
typedef float f32x16 __attribute__((ext_vector_type(16)));

__device__ __forceinline__ float bf2f(unsigned int u16) {
  return __uint_as_float(u16 << 16);
}
__device__ __forceinline__ unsigned short f2bf(float f) {
  unsigned int u = __float_as_uint(f);
  u += 0x7fff + ((u >> 16) & 1);  // RNE
  return (unsigned short)(u >> 16);
}

__device__ __forceinline__ float wave_sum(float v) {
#pragma unroll
  for (int o = 32; o; o >>= 1) v += __shfl_down(v, o, 64);
  return v;
}

// async 16B/lane global->LDS. LDS dest = wave-uniform base + lane*16.
__device__ __forceinline__ void gload_lds16(const bf16_t* g, bf16_t* l) {
  __builtin_amdgcn_global_load_lds(
      (const __attribute__((address_space(1))) unsigned int*)(unsigned long long)(const void*)g,
      (__attribute__((address_space(3))) unsigned int*)(unsigned int)(unsigned long long)(void*)l,
      16, 0, 0);
}

// ---------------- merged weight transpose: WT[n][k] = bf16(W[k][n]) -------
__global__ __launch_bounds__(256) void transpose_all_kernel(
    const float* __restrict__ w_qkv, bf16_t* __restrict__ wt_qkv,
    const float* __restrict__ w_o, bf16_t* __restrict__ wt_o,
    const float* __restrict__ w_m1, bf16_t* __restrict__ wt_m1,
    const float* __restrict__ w_m2, bf16_t* __restrict__ wt_m2) {
  int g = blockIdx.x;
  const float* W;
  bf16_t* WT;
  int N, bx, by;
  if (g < 3072) {
    W = w_qkv; WT = wt_qkv; N = 3072;
    bx = g % 96; by = g / 96;
  } else {
    int r = g - 3072;
    int which = r >> 10, l = r & 1023;
    bx = l & 31; by = l >> 5; N = 1024;
    W = (which == 0) ? w_o : (which == 1) ? w_m1 : w_m2;
    WT = (which == 0) ? wt_o : (which == 1) ? wt_m1 : wt_m2;
  }
  __shared__ float t[32][33];
  int n0 = bx * 32, k0 = by * 32;
  int tx = threadIdx.x, ty = threadIdx.y;
#pragma unroll
  for (int i = 0; i < 4; i++)
    t[ty + i * 8][tx] = W[(size_t)(k0 + ty + i * 8) * N + n0 + tx];
  __syncthreads();
#pragma unroll
  for (int i = 0; i < 4; i++)
    WT[(size_t)(n0 + ty + i * 8) * 1024 + k0 + tx] = f2bf(t[tx][ty + i * 8]);
}

// ---------------- PE table ------------------------------------------------
__global__ void pe_kernel(float* __restrict__ pe) {
  int s = blockIdx.x;
  double pos = 6.283185307179586476925286766559 * (double)s;
  for (int p = threadIdx.x; p < HD / 2; p += blockDim.x) {
    double dv = exp((double)(2 * p) * (-9.210340371976184 / (double)HD));
    double a = pos * dv;
    pe[s * HD + 2 * p] = (float)sin(a);
    pe[s * HD + 2 * p + 1] = (float)cos(a);
  }
}

// ---------------- x = bf16(LN(concat(cls, z^T) + pe)) ---------------------
__global__ __launch_bounds__(256) void build_x_kernel(
    const float* __restrict__ z, const float* __restrict__ cls,
    const float* __restrict__ pe, const float* __restrict__ g,
    const float* __restrict__ be, bf16_t* __restrict__ x) {
  int t = blockIdx.x;
  int b = t / S1, s = t % S1;
  const float* src = (s == 0) ? cls : (z + ((size_t)(s - 1) * BATCH + b) * HD);
  const float* pr = pe + (size_t)s * HD;
  int tid = threadIdx.x;
  float vals[4];
  float sum = 0.f, sq = 0.f;
#pragma unroll
  for (int i = 0; i < 4; i++) {
    int h = tid + i * 256;
    float v = src[h] + pr[h];
    vals[i] = v;
    sum += v;
    sq += v * v;
  }
  __shared__ float shs[4], shq[4];
  __shared__ float sm, sr;
  sum = wave_sum(sum);
  sq = wave_sum(sq);
  int wave = tid >> 6, lane = tid & 63;
  if (!lane) { shs[wave] = sum; shq[wave] = sq; }
  __syncthreads();
  if (!tid) {
    float S = shs[0] + shs[1] + shs[2] + shs[3];
    float Q = shq[0] + shq[1] + shq[2] + shq[3];
    float mean = S * (1.f / HD);
    float var = Q * (1.f / HD) - mean * mean;
    sm = mean;
    sr = rsqrtf(var + 1e-5f);
  }
  __syncthreads();
  float mean = sm, rstd = sr;
  bf16_t* xr = x + (size_t)t * HD;
#pragma unroll
  for (int i = 0; i < 4; i++) {
    int h = tid + i * 256;
    xr[h] = f2bf((vals[i] - mean) * rstd * g[h] + be[h]);
  }
}

// ---------------- zsa = bf16(LN(sa + x)) ----------------------------------
__global__ __launch_bounds__(256) void ln_residual_kernel(
    const bf16_t* __restrict__ a, const bf16_t* __restrict__ r,
    const float* __restrict__ g, const float* __restrict__ be,
    bf16_t* __restrict__ out) {
  int t = blockIdx.x;
  int tid = threadIdx.x;
  const bf16_t* ar = a + (size_t)t * QKVLD;
  const bf16_t* rr = r + (size_t)t * HD;
  float vals[4];
  float sum = 0.f, sq = 0.f;
#pragma unroll
  for (int i = 0; i < 4; i++) {
    int h = tid + i * 256;
    float v = bf2f(ar[h]) + bf2f(rr[h]);
    vals[i] = v;
    sum += v;
    sq += v * v;
  }
  __shared__ float shs[4], shq[4];
  __shared__ float sm, sr;
  sum = wave_sum(sum);
  sq = wave_sum(sq);
  int wave = tid >> 6, lane = tid & 63;
  if (!lane) { shs[wave] = sum; shq[wave] = sq; }
  __syncthreads();
  if (!tid) {
    float S = shs[0] + shs[1] + shs[2] + shs[3];
    float Q = shq[0] + shq[1] + shq[2] + shq[3];
    float mean = S * (1.f / HD);
    float var = Q * (1.f / HD) - mean * mean;
    sm = mean;
    sr = rsqrtf(var + 1e-5f);
  }
  __syncthreads();
  float mean = sm, rstd = sr;
  bf16_t* outp = out + (size_t)t * QKVLD;
#pragma unroll
  for (int i = 0; i < 4; i++) {
    int h = tid + i * 256;
    outp[h] = f2bf((vals[i] - mean) * rstd * g[h] + be[h]);
  }
}

// ---------------- QKV GEMM: 128x128, BK=64, 32x32x16 MFMA -----------------
// Round-7 kernel (measured 150us) + bank-conflict de-aliasing: the second
// 16-row staging unit uses granule permutation XOR'd by 2 (scol^2 on the
// gA1/gB1 SOURCE), and fragment reads add ^(2*((row>>4)&1)). This makes the
// two 16-row chunks of a 32-row fragment read use different slot
// assignments (the property the conflict-free 16x16 pattern has via its
// lane>>4 XOR term). Staging/read remain a consistent involution.
__global__ __launch_bounds__(256) void gemm32_qkv_kernel(
    const bf16_t* __restrict__ A, int lda, const bf16_t* __restrict__ WT,
    const float* __restrict__ bias, bf16_t* __restrict__ C, int ldc) {
  constexpr int K = 1024;
  __shared__ bf16_t SMEM[16384];  // K-loop: A [0,8192) B [8192,16384); epi: C tile
  bf16_t* As = SMEM;
  bf16_t* Bs = SMEM + 8192;
  int tid = threadIdx.x;
  int w = tid >> 6, lane = tid & 63;
  int wm = w >> 1, wn = w & 1;
  int m0 = blockIdx.y * 128, n0 = blockIdx.x * 128;

  int srow = lane >> 2;
  int scol0 = ((lane & 3) ^ ((lane >> 3) & 3)) * 8;        // unit0 mask m
  int scol1 = ((lane & 3) ^ ((lane >> 3) & 3) ^ 2) * 8;    // unit1 mask m^2
  const bf16_t* gA0 = A + (size_t)(m0 + w * 32 + srow) * lda + scol0;
  const bf16_t* gA1 = A + (size_t)(m0 + w * 32 + 16 + srow) * lda + scol1;
  const bf16_t* gB0 = WT + (size_t)(n0 + w * 32 + srow) * K + scol0;
  const bf16_t* gB1 = WT + (size_t)(n0 + w * 32 + 16 + srow) * K + scol1;
  bf16_t* lA0 = As + (w * 32) * 32;
  bf16_t* lA1 = As + (w * 32 + 16) * 32;
  bf16_t* lB0 = Bs + (w * 32) * 32;
  bf16_t* lB1 = Bs + (w * 32 + 16) * 32;

  // 32x32x16 fragment offsets: row = lane&31, k-granule = 2h+(lane>>5),
  // de-swizzled with mask ((row>>1)&3) ^ 2*((row>>4)&1).
  int r32 = lane & 31, g5 = lane >> 5;
  int aoff[2][2], boff[2][2];  // [tile][h]
#pragma unroll
  for (int mi = 0; mi < 2; mi++) {
    int arow = wm * 64 + mi * 32 + r32;
    int brow = wn * 64 + mi * 32 + r32;
    int ma = ((arow >> 1) & 3) ^ (2 * ((arow >> 4) & 1));
    int mb = ((brow >> 1) & 3) ^ (2 * ((brow >> 4) & 1));
#pragma unroll
    for (int h = 0; h < 2; h++) {
      aoff[mi][h] = arow * 32 + ((2 * h + g5) ^ ma) * 8;
      boff[mi][h] = brow * 32 + ((2 * h + g5) ^ mb) * 8;
    }
  }

  f32x16 acc[2][2] = {};

  for (int k0 = 0; k0 < K; k0 += 64) {
    gload_lds16(gA0, lA0);
    gload_lds16(gA1, lA1);
    gload_lds16(gB0, lB0);
    gload_lds16(gB1, lB1);
    gload_lds16(gA0 + 32, lA0 + 4096);
    gload_lds16(gA1 + 32, lA1 + 4096);
    gload_lds16(gB0 + 32, lB0 + 4096);
    gload_lds16(gB1 + 32, lB1 + 4096);
    gA0 += 64; gA1 += 64; gB0 += 64; gB1 += 64;
    __syncthreads();
#pragma unroll
    for (int p = 0; p < 2; p++) {
      s16x8 af[2][2], bf[2][2];
#pragma unroll
      for (int t = 0; t < 2; t++)
#pragma unroll
        for (int h = 0; h < 2; h++) {
          af[t][h] = *(const s16x8*)(As + p * 4096 + aoff[t][h]);
          bf[t][h] = *(const s16x8*)(Bs + p * 4096 + boff[t][h]);
        }
#pragma unroll
      for (int mi = 0; mi < 2; mi++)
#pragma unroll
        for (int nj = 0; nj < 2; nj++)
#pragma unroll
          for (int h = 0; h < 2; h++)
            acc[mi][nj] = __builtin_amdgcn_mfma_f32_32x32x16_bf16(
                af[mi][h], bf[nj][h], acc[mi][nj], 0, 0, 0);
    }
    __syncthreads();
  }

  // stage C tile (bf16) in SMEM, then full-line coalesced uint4 stores.
  // C/D (m101): col=lane&31, row=(r&3)+8*(r>>2)+4*(lane>>5).
#pragma unroll
  for (int nj = 0; nj < 2; nj++) {
    int cn = wn * 64 + nj * 32 + r32;
    float bb = bias[n0 + cn];
#pragma unroll
    for (int mi = 0; mi < 2; mi++) {
#pragma unroll
      for (int r = 0; r < 16; r++) {
        int rrow = (r & 3) + 8 * (r >> 2) + 4 * g5;
        int cm = wm * 64 + mi * 32 + rrow;
        SMEM[cm * 128 + cn] = f2bf(acc[mi][nj][r] + bb);
      }
    }
  }
  __syncthreads();
  int rr = tid >> 4, cb = (tid & 15) * 8;
#pragma unroll
  for (int p = 0; p < 8; p++) {
    int row = p * 16 + rr;
    *(uint4*)(C + (size_t)(m0 + row) * ldc + n0 + cb) =
        *(const uint4*)(SMEM + row * 128 + cb);
  }
}

// ---------------- small GEMMs: 128x128, BK=64, 16x16x32 (round-6 proven) --
// EPI: 0 = bias, 1 = bias+GELU (LDS-staged coalesced store),
//      2 = bias+residual -> f32 out (s,b swizzle). XCD-bijective swizzle.
template <int EPI>
__global__ __launch_bounds__(256) void mfma_gemm_kernel(
    const bf16_t* __restrict__ A, int lda, const bf16_t* __restrict__ WT,
    const float* __restrict__ bias, bf16_t* __restrict__ C, int ldc,
    const bf16_t* __restrict__ res, float* __restrict__ outf) {
  constexpr int K = 1024;
  __shared__ bf16_t SMEM[16384];
  bf16_t* As = SMEM;
  bf16_t* Bs = SMEM + 8192;
  int tid = threadIdx.x;
  int w = tid >> 6, lane = tid & 63;
  int wm = w >> 1, wn = w & 1;

  int nwg = gridDim.x * gridDim.y;
  int g = blockIdx.y * gridDim.x + blockIdx.x;
  int swz = (g & 7) * (nwg >> 3) + (g >> 3);
  int bx = swz % gridDim.x, by = swz / gridDim.x;
  int m0 = by * 128, n0 = bx * 128;

  int srow = lane >> 2;
  int scol = ((lane & 3) ^ ((lane >> 3) & 3)) * 8;
  const bf16_t* gA0 = A + (size_t)(m0 + w * 32 + srow) * lda + scol;
  const bf16_t* gA1 = gA0 + (size_t)16 * lda;
  const bf16_t* gB0 = WT + (size_t)(n0 + w * 32 + srow) * K + scol;
  const bf16_t* gB1 = gB0 + (size_t)16 * K;
  bf16_t* lA0 = As + (w * 32) * 32;
  bf16_t* lA1 = As + (w * 32 + 16) * 32;
  bf16_t* lB0 = Bs + (w * 32) * 32;
  bf16_t* lB1 = Bs + (w * 32 + 16) * 32;

  int frow = lane & 15;
  int slot = (lane >> 4) ^ ((frow >> 1) & 3);
  int aoff[4], boff[4];
#pragma unroll
  for (int t = 0; t < 4; t++) {
    aoff[t] = (wm * 64 + t * 16 + frow) * 32 + slot * 8;
    boff[t] = (wn * 64 + t * 16 + frow) * 32 + slot * 8;
  }

  f32x4 acc[4][4] = {};

  for (int k0 = 0; k0 < K; k0 += 64) {
    gload_lds16(gA0, lA0);
    gload_lds16(gA1, lA1);
    gload_lds16(gB0, lB0);
    gload_lds16(gB1, lB1);
    gload_lds16(gA0 + 32, lA0 + 4096);
    gload_lds16(gA1 + 32, lA1 + 4096);
    gload_lds16(gB0 + 32, lB0 + 4096);
    gload_lds16(gB1 + 32, lB1 + 4096);
    gA0 += 64; gA1 += 64; gB0 += 64; gB1 += 64;
    __syncthreads();
#pragma unroll
    for (int p = 0; p < 2; p++) {
      s16x8 af[4], bf[4];
#pragma unroll
      for (int t = 0; t < 4; t++) {
        af[t] = *(const s16x8*)(As + p * 4096 + aoff[t]);
        bf[t] = *(const s16x8*)(Bs + p * 4096 + boff[t]);
      }
#pragma unroll
      for (int i = 0; i < 4; i++)
#pragma unroll
        for (int j = 0; j < 4; j++)
          acc[i][j] = __builtin_amdgcn_mfma_f32_16x16x32_bf16(af[i], bf[j], acc[i][j], 0, 0, 0);
    }
    __syncthreads();
  }

  int erow = (lane >> 4) * 4, ecol = lane & 15;
  if (EPI == 2) {
#pragma unroll
    for (int j = 0; j < 4; j++) {
      int n = n0 + wn * 64 + j * 16 + ecol;
      float bb = bias[n];
#pragma unroll
      for (int i = 0; i < 4; i++) {
        int mb = m0 + wm * 64 + i * 16 + erow;
#pragma unroll
        for (int r = 0; r < 4; r++) {
          int m = mb + r;
          int b = m / S1, s = m % S1;
          float v = acc[i][j][r] + bb + bf2f(res[(size_t)m * QKVLD + n]);
          outf[((size_t)s * BATCH + b) * HD + n] = v;
        }
      }
    }
  } else {
#pragma unroll
    for (int j = 0; j < 4; j++) {
      int cn = wn * 64 + j * 16 + ecol;
      float bb = bias[n0 + cn];
#pragma unroll
      for (int i = 0; i < 4; i++) {
        int cmb = wm * 64 + i * 16 + erow;
#pragma unroll
        for (int r = 0; r < 4; r++) {
          float v = acc[i][j][r] + bb;
          if (EPI == 1) v = 0.5f * v * (1.f + erff(v * 0.7071067811865476f));
          SMEM[(cmb + r) * 128 + cn] = f2bf(v);
        }
      }
    }
    __syncthreads();
    int rr = tid >> 4, cb = (tid & 15) * 8;
#pragma unroll
    for (int p = 0; p < 8; p++) {
      int row = p * 16 + rr;
      *(uint4*)(C + (size_t)(m0 + row) * ldc + n0 + cb) =
          *(const uint4*)(SMEM + row * 128 + cb);
    }
  }
}

// ---------------- tiled band attention: MFMA QK^T + LDS softmax + VALU PV -
__global__ __launch_bounds__(256) void attn_tile_kernel(bf16_t* __restrict__ qkv) {
  int g = blockIdx.x;
  int xcd = g & 7, tt0 = g >> 3;
  int qt = tt0 % 5, b = xcd + 8 * (tt0 / 5);
  int q0 = qt * 32;

  int lo_col = (qt == 0) ? 0 : (q0 - 20);
  int hi_col = (qt == 0) ? 150 : ((q0 + 51 < 150) ? q0 + 51 : 150);
  int ct0 = lo_col >> 5;
  int cth = (hi_col + 31) >> 5;
  int NCT = cth - ct0;       // 5,3,3,3,2
  int W = NCT * 32;          // score width
  int NSUB = NCT * 2;        // 16-wide column subtiles
  int NT = 2 * NSUB;         // total 16x16 tiles (20,12,12,12,8)
  int T = NT >> 2;           // tiles per wave (5,3,3,3,2)

  __shared__ bf16_t Qs[2 * 32 * 32];    // 2 k-planes of Q tile
  __shared__ bf16_t Ks[2 * 160 * 32];   // 2 k-planes of K band
  __shared__ float S[32][164];          // scores -> probs (f32)

  int tid = threadIdx.x;
  int w = tid >> 6, lane = tid & 63;

  const bf16_t* kvbase = qkv + (size_t)b * S1 * QKVLD;

  int sr = lane >> 2;                                 // row within 16-row unit
  int scol = ((lane & 3) ^ ((lane >> 3) & 3)) * 8;    // swizzled 8-elem slot
  int frow = lane & 15;
  int fslot = (((lane >> 4) ^ ((frow >> 1) & 3))) * 8;

  f32x4 acc[5] = {};

  int U1 = 2 + NSUB;  // 16-row staging units per k-plane (Q:2, K:NSUB)

  for (int k0 = 0; k0 < 1024; k0 += 64) {
    for (int uu = w; uu < 2 * U1; uu += 4) {
      int p = (uu >= U1) ? 1 : 0;
      int ur = uu - p * U1;
      int col = k0 + p * 32 + scol;
      if (ur < 2) {
        int qrow = q0 + ur * 16 + sr;
        if (qrow > 149) qrow = 149;
        gload_lds16(kvbase + (size_t)qrow * QKVLD + col,
                    Qs + p * 1024 + (ur * 16) * 32);
      } else {
        int cr0 = (ur - 2) * 16;             // c_rel row base of unit
        int cg = ct0 * 32 + cr0 + sr;
        if (cg > 149) cg = 149;
        gload_lds16(kvbase + (size_t)cg * QKVLD + HD + col,
                    Ks + p * 5120 + cr0 * 32);
      }
    }
    __syncthreads();
    s16x8 af0[2], af1[2];
#pragma unroll
    for (int p = 0; p < 2; p++) {
      af0[p] = *(const s16x8*)(Qs + p * 1024 + (0 * 16 + frow) * 32 + fslot);
      af1[p] = *(const s16x8*)(Qs + p * 1024 + (1 * 16 + frow) * 32 + fslot);
    }
#pragma unroll
    for (int t = 0; t < 5; t++) {
      if (t < T) {
        int tidt = w + t * 4;
        int qs = (tidt >= NSUB) ? 1 : 0;
        int cs = tidt - qs * NSUB;
#pragma unroll
        for (int p = 0; p < 2; p++) {
          s16x8 bf = *(const s16x8*)(Ks + p * 5120 + (cs * 16 + frow) * 32 + fslot);
          s16x8 a = qs ? af1[p] : af0[p];
          acc[t] = __builtin_amdgcn_mfma_f32_16x16x32_bf16(a, bf, acc[t], 0, 0, 0);
        }
      }
    }
    __syncthreads();
  }

  // write scores to LDS with mask+scale fused (C/D: col=lane&15, row=(lane>>4)*4+r)
  int erow = (lane >> 4) * 4, ecol = lane & 15;
#pragma unroll
  for (int t = 0; t < 5; t++) {
    if (t < T) {
      int tidt = w + t * 4;
      int qs = (tidt >= NSUB) ? 1 : 0;
      int cs = tidt - qs * NSUB;
#pragma unroll
      for (int r = 0; r < 4; r++) {
        int qrel = qs * 16 + erow + r;
        int crel = cs * 16 + ecol;
        int qg = q0 + qrel, cg = ct0 * 32 + crel;
        bool ok = (qg < 150) && (cg < 150) &&
                  ((qg == 0) || (cg >= qg - WIN && cg < qg + WIN));
        S[qrel][crel] = ok ? acc[t][r] * 0.03125f : -1e30f;
      }
    }
  }
  __syncthreads();

  // softmax: 8 threads per query row, shfl_xor reduce over 8 lanes
  {
    int q = tid >> 3, j = tid & 7;
    float m = -1e30f;
    for (int c = j; c < W; c += 8) m = fmaxf(m, S[q][c]);
#pragma unroll
    for (int o = 1; o < 8; o <<= 1) m = fmaxf(m, __shfl_xor(m, o, 64));
    float s = 0.f;
    for (int c = j; c < W; c += 8) {
      float e = __expf(S[q][c] - m);
      S[q][c] = e;
      s += e;
    }
#pragma unroll
    for (int o = 1; o < 8; o <<= 1) s += __shfl_xor(s, o, 64);
    float inv = 1.f / s;
    for (int c = j; c < W; c += 8) S[q][c] *= inv;
  }
  __syncthreads();

  // PV: wave owns an 8-query octet; P broadcast from LDS, V coalesced from L2.
  // cls octet (qt==0, w==0): row 0 attends to ALL columns -> full range;
  // rows 1..7 of that octet are safe since their masked probs are exactly 0.
  int qg0 = q0 + 8 * w;
  if (qg0 < 150) {
    int lo = (qt == 0 && w == 0) ? 0 : ((qg0 - WIN > 0) ? qg0 - WIN : 0);
    int hi = (qt == 0 && w == 0) ? 150 : ((qg0 + 27 < 150) ? qg0 + 27 : 150);
    int c0base = ct0 * 32;
#pragma unroll
    for (int hp = 0; hp < 2; hp++) {
      int hb = hp * 512 + lane * 8;
      float a[8][8];
#pragma unroll
      for (int qi = 0; qi < 8; qi++)
#pragma unroll
        for (int e = 0; e < 8; e++) a[qi][e] = 0.f;
      const bf16_t* vb = kvbase + 2 * HD + hb;
      for (int c = lo; c < hi; ++c) {
        uint4 vv = *(const uint4*)(vb + (size_t)c * QKVLD);
        float vf[8];
        vf[0] = __uint_as_float(vv.x << 16);
        vf[1] = __uint_as_float(vv.x & 0xffff0000u);
        vf[2] = __uint_as_float(vv.y << 16);
        vf[3] = __uint_as_float(vv.y & 0xffff0000u);
        vf[4] = __uint_as_float(vv.z << 16);
        vf[5] = __uint_as_float(vv.z & 0xffff0000u);
        vf[6] = __uint_as_float(vv.w << 16);
        vf[7] = __uint_as_float(vv.w & 0xffff0000u);
        int crel = c - c0base;
#pragma unroll
        for (int qi = 0; qi < 8; qi++) {
          float p = S[8 * w + qi][crel];
#pragma unroll
          for (int e = 0; e < 8; e++) a[qi][e] += p * vf[e];
        }
      }
#pragma unroll
      for (int qi = 0; qi < 8; qi++) {
        int qg = qg0 + qi;
        if (qg < 150) {
          uint4 pk;
          pk.x = (unsigned int)f2bf(a[qi][0]) | ((unsigned int)f2bf(a[qi][1]) << 16);
          pk.y = (unsigned int)f2bf(a[qi][2]) | ((unsigned int)f2bf(a[qi][3]) << 16);
          pk.z = (unsigned int)f2bf(a[qi][4]) | ((unsigned int)f2bf(a[qi][5]) << 16);
          pk.w = (unsigned int)f2bf(a[qi][6]) | ((unsigned int)f2bf(a[qi][7]) << 16);
          *(uint4*)(qkv + ((size_t)b * S1 + qg) * QKVLD + hb) = pk;
        }
      }
    }
  }
}

extern "C" void kernel_launch(void* const* d_in, const int* in_sizes, int n_in,
                              void* d_out, int out_size, void* d_ws, size_t ws_size,
                              hipStream_t stream) {
  (void)in_sizes; (void)n_in; (void)out_size; (void)ws_size;
  const float* z = (const float*)d_in[0];
  const float* cls = (const float*)d_in[1];
  const float* ln_g = (const float*)d_in[2];
  const float* ln_b = (const float*)d_in[3];
  const float* w_qkv = (const float*)d_in[4];
  const float* b_qkv = (const float*)d_in[5];
  const float* w_o = (const float*)d_in[6];
  const float* b_o = (const float*)d_in[7];
  const float* w_m1 = (const float*)d_in[8];
  const float* b_m1 = (const float*)d_in[9];
  const float* w_m2 = (const float*)d_in[10];
  const float* b_m2 = (const float*)d_in[11];

  // ws: [wt_m2 2MB][pe 0.6MB][qkv 118MB] = ~120.7 MB
  char* wsb = (char*)d_ws;
  bf16_t* wt_m2 = (bf16_t*)wsb;
  float* pe = (float*)(wsb + 2097152);
  bf16_t* qkv = (bf16_t*)(wsb + 2097152 + 614400);

  // d_out scratch: [x bf16 39.3MB][wt_qkv 6.3MB][wt_o 2MB][wt_m1 2MB]
  char* outb = (char*)d_out;
  bf16_t* x = (bf16_t*)outb;
  bf16_t* wt_qkv = (bf16_t*)(outb + 39321600);
  bf16_t* wt_o = (bf16_t*)(outb + 45613056);
  bf16_t* wt_m1 = (bf16_t*)(outb + 47710208);

  bf16_t* av = qkv;            // attention writes over Q slice
  bf16_t* sa = qkv + HD;       // over K slice
  bf16_t* zsa = qkv + 2 * HD;  // over V slice
  bf16_t* h1 = qkv;            // over Q slice (av dead)
  float* out = (float*)d_out;

  transpose_all_kernel<<<6144, dim3(32, 8), 0, stream>>>(
      w_qkv, wt_qkv, w_o, wt_o, w_m1, wt_m1, w_m2, wt_m2);
  pe_kernel<<<S1, 256, 0, stream>>>(pe);
  build_x_kernel<<<MTOK, 256, 0, stream>>>(z, cls, pe, ln_g, ln_b, x);
  gemm32_qkv_kernel<<<dim3(24, 150), 256, 0, stream>>>(
      x, HD, wt_qkv, b_qkv, qkv, QKVLD);
  attn_tile_kernel<<<640, 256, 0, stream>>>(qkv);
  mfma_gemm_kernel<0><<<dim3(8, 150), 256, 0, stream>>>(
      av, QKVLD, wt_o, b_o, sa, QKVLD, nullptr, nullptr);
  ln_residual_kernel<<<MTOK, 256, 0, stream>>>(sa, x, ln_g, ln_b, zsa);
  mfma_gemm_kernel<1><<<dim3(8, 150), 256, 0, stream>>>(
      zsa, QKVLD, wt_m1, b_m1, h1, QKVLD, nullptr, nullptr);
  mfma_gemm_kernel<2><<<dim3(8, 150), 256, 0, stream>>>(
      h1, QKVLD, wt_m2, b_m2, nullptr, 0, zsa, out);
}